// Round 4
// baseline (220.632 us; speedup 1.0000x reference)
//
#include <hip/hip_runtime.h>

// Depthwise Gaussian blur K=121, replicate pad, separable, fp32. FUSED.
// R11 = R10's 16-col-span H phase (17 group loads/lane, conflicts -62%)
// + store fix: R10 stored 16B/lane at 64B lane stride -> partial-sector
// writes, WRITE_SIZE 27->91MB + write-allocate fetches (+13MB), dur 56->75.
// Now the 8x512 output tile round-trips through LDS (sm is dead after the
// H loop): swizzled b128 writes at the bank floor, barrier, then LINEAR
// stores -- thread t, pass p stores float4 at unit p*256+t: each store
// instr = 1KB contiguous per wave, full 128B lines.
// Kept: 16B-unit XOR swizzle zero-pad LDS, deferred normalization,
// interior clamp-free V path, XCD swizzle.

#define HH    512
#define WW    512
#define PLANE (512 * 512)
#define NIMG  24
#define ROWF  640                    // 160 16B-units/row, swizzle-bijective

__device__ __forceinline__ void make_weights(const float* __restrict__ sigma,
                                             float* __restrict__ wlds, int tid) {
    if (tid < 128) {
        const float s = sigma[0] * 8.0f + 16.0f;
        const float inv2v = 1.0f / (2.0f * s * s);
        float g = 0.0f;
        if (tid < 121) {
            const float c = (float)tid - 60.0f;
            g = __expf(-c * c * inv2v);
        }
        wlds[tid] = g;               // UNNORMALIZED; taps 121..127 exactly 0
    }
}

// dword offset within an LDS row for padded column `col` (swizzled)
__device__ __forceinline__ int swz_off(int col) {
    const int u = col >> 2;
    return ((u ^ ((u >> 3) & 7)) << 2) + (col & 3);
}

// Vertical octet, clamped rows (boundary tiles)
#define V_OCT(CUR, NXT, KO)                                               \
    { *(float4*)&wq[0] = *(const float4*)&wlds[(KO) * 8];                 \
      *(float4*)&wq[4] = *(const float4*)&wlds[(KO) * 8 + 4];             \
      _Pragma("unroll")                                                   \
      for (int ki = 0; ki < 8; ++ki) {                                    \
          int rr = r0 - 52 + (KO) * 8 + ki;                               \
          rr = rr < 0 ? 0 : (rr > HH - 1 ? HH - 1 : rr);                  \
          NXT[ki] = *(const float2*)&src[(size_t)rr * WW];                \
          const float wk = wq[ki];                                        \
          _Pragma("unroll")                                               \
          for (int j = 0; j < 8; ++j) {                                   \
              const int idx = ki + j;                                     \
              const float2 v = (idx < 8) ? CUR[idx] : NXT[idx - 8];       \
              vac[j].x += wk * v.x; vac[j].y += wk * v.y;                 \
          }                                                               \
      }                                                                   \
    }

// Vertical octet, no clamp (interior tiles): running row pointer pv
#define V_OCT_NC(CUR, NXT, KO)                                            \
    { *(float4*)&wq[0] = *(const float4*)&wlds[(KO) * 8];                 \
      *(float4*)&wq[4] = *(const float4*)&wlds[(KO) * 8 + 4];             \
      _Pragma("unroll")                                                   \
      for (int ki = 0; ki < 8; ++ki) {                                    \
          NXT[ki] = *(const float2*)pv; pv += WW;                         \
          const float wk = wq[ki];                                        \
          _Pragma("unroll")                                               \
          for (int j = 0; j < 8; ++j) {                                   \
              const int idx = ki + j;                                     \
              const float2 v = (idx < 8) ? CUR[idx] : NXT[idx - 8];       \
              vac[j].x += wk * v.x; vac[j].y += wk * v.y;                 \
          }                                                               \
      }                                                                   \
    }

// Load group G (8 floats): phys(2G+1) = phys(2G)^1 -> one addr calc / 2 b128
#define LOADG(D, G)                                                       \
    { const int u_  = 2 * (G);                                            \
      const int o1_ = (u_ ^ ((u_ >> 3) & 7)) << 2;                        \
      *(float4*)&D[0] = *(const float4*)(bs + o1_);                       \
      *(float4*)&D[4] = *(const float4*)(bs + (o1_ ^ 4)); }

// One octet over a contiguous 16-col span; window groups A0..A2, prefetch A3
#define H_OCT(A0, A1, A2, A3, KO)                                         \
    { LOADG(A3, 2 * L + (KO) + 3)                                         \
      *(float4*)&wq[0] = *(const float4*)&wlds[(KO) * 8];                 \
      *(float4*)&wq[4] = *(const float4*)&wlds[(KO) * 8 + 4];             \
      _Pragma("unroll")                                                   \
      for (int ki = 0; ki < 8; ++ki) {                                    \
          const float wk = wq[ki];                                        \
          _Pragma("unroll")                                               \
          for (int j = 0; j < 16; ++j) {                                  \
              const int idx = ki + j;                                     \
              const float v = (idx < 8) ? A0[idx]                         \
                            : (idx < 16) ? A1[idx - 8] : A2[idx - 16];    \
              acc[j] += wk * v;                                           \
          }                                                               \
      }                                                                   \
    }

// Final octet: no prefetch (group 2L+18 would run past the row)
#define H_OCT_NP(A0, A1, A2, A3, KO)                                      \
    { *(float4*)&wq[0] = *(const float4*)&wlds[(KO) * 8];                 \
      *(float4*)&wq[4] = *(const float4*)&wlds[(KO) * 8 + 4];             \
      _Pragma("unroll")                                                   \
      for (int ki = 0; ki < 8; ++ki) {                                    \
          const float wk = wq[ki];                                        \
          _Pragma("unroll")                                               \
          for (int j = 0; j < 16; ++j) {                                  \
              const int idx = ki + j;                                     \
              const float v = (idx < 8) ? A0[idx]                         \
                            : (idx < 16) ? A1[idx - 8] : A2[idx - 16];    \
              acc[j] += wk * v;                                           \
          }                                                               \
      }                                                                   \
    }

__global__ __launch_bounds__(256, 6) void blur_fused(
        const float* __restrict__ x, const float* __restrict__ sigma,
        float* __restrict__ out) {
    __shared__ float sm[8 * ROWF];                   // 20480 B
    __shared__ float wlds[128];
    const int tid = threadIdx.x;

    // XCD swizzle: linear id -> contiguous 192-tile span per XCD (%8 rr).
    const int lid   = blockIdx.x + gridDim.x * blockIdx.y;   // 0..1535
    const int tile  = (lid & 7) * 192 + (lid >> 3);
    const int r0    = (tile & 63) * 8;               // output rows r0..r0+7
    const int plane = tile >> 6;

    const int c0 = tid * 2;                          // this thread's 2 cols
    const float* __restrict__ src = x + (size_t)plane * PLANE + c0;

    // ---- vertical: 8 rows x 2 cols per thread, global-streamed window ----
    float2 wa[8], wb[8], vac[8];
    float  wq[8];
    const bool interior = (r0 >= 64) && (r0 <= 432);   // rows r0-60..r0+75 in-range
    if (interior) {
        const float* pp = src + (size_t)(r0 - 60) * WW;
        #pragma unroll
        for (int m = 0; m < 8; ++m) { wa[m] = *(const float2*)pp; pp += WW; }
    } else {
        #pragma unroll
        for (int m = 0; m < 8; ++m) {                // rows r0-60..r0-53
            int rr = r0 - 60 + m;
            rr = rr < 0 ? 0 : rr;
            wa[m] = *(const float2*)&src[(size_t)rr * WW];
        }
    }
    make_weights(sigma, wlds, tid);                  // overlaps loads in flight
    #pragma unroll
    for (int j = 0; j < 8; ++j) vac[j] = make_float2(0.f, 0.f);
    __syncthreads();                                 // wlds ready

    // normalizer: S = sum of taps, once per wave (butterfly), scale at end
    const int lane = tid & 63;
    float s_sum = wlds[lane] + wlds[lane + 64];
    #pragma unroll
    for (int o = 32; o >= 1; o >>= 1) s_sum += __shfl_xor(s_sum, o);
    const float inv_s2 = 1.0f / (s_sum * s_sum);

    if (interior) {
        const float* pv = src + (size_t)(r0 - 52) * WW;
        #pragma unroll 1
        for (int ko = 0; ko < 16; ko += 2) {
            V_OCT_NC(wa, wb, ko)
            V_OCT_NC(wb, wa, ko + 1)
        }
    } else {
        #pragma unroll 1
        for (int ko = 0; ko < 16; ko += 2) {
            V_OCT(wa, wb, ko)
            V_OCT(wb, wa, ko + 1)
        }
    }

    // write intermediate at halo offset +60 (swizzled; float2 stays in-unit)
    {
        const int off = swz_off(c0 + 60);            // col even -> within-unit
        #pragma unroll
        for (int j = 0; j < 8; ++j)
            *(float2*)&sm[j * ROWF + off] = vac[j];
    }
    __syncthreads();

    // ---- halo: cols 0..59 <- col 60; 572..639 <- col 571 -----------------
    // (cols 632..639 are only touched by zero taps; replicate value is fine)
    if (tid < 32) {
        const int p = (tid < 15) ? tid * 4 : 572 + (tid - 15) * 4;
        const int u   = p >> 2;
        const int off = (u ^ ((u >> 3) & 7)) << 2;   // 16B-aligned
        const int soff = (tid < 15) ? swz_off(60) : swz_off(571);
        #pragma unroll
        for (int r8 = 0; r8 < 8; ++r8) {
            const float v = sm[r8 * ROWF + soff];
            *(float4*)&sm[r8 * ROWF + off] = make_float4(v, v, v, v);
        }
    }
    __syncthreads();

    // ---- horizontal: ONE contiguous 16-col span per lane -----------------
    const int r = tid >> 5;                          // 0..7
    const int L = tid & 31;                          // span cols 16L..16L+15
    const float* __restrict__ bs = sm + r * ROWF;

    float a0[8], a1[8], a2[8], a3[8];
    float acc[16];
    #pragma unroll
    for (int j = 0; j < 16; ++j) acc[j] = 0.0f;

    LOADG(a0, 2 * L)
    LOADG(a1, 2 * L + 1)
    LOADG(a2, 2 * L + 2)

    #pragma unroll 1
    for (int ko = 0; ko < 12; ko += 4) {
        H_OCT(a0, a1, a2, a3, ko)
        H_OCT(a1, a2, a3, a0, ko + 1)
        H_OCT(a2, a3, a0, a1, ko + 2)
        H_OCT(a3, a0, a1, a2, ko + 3)
    }
    H_OCT   (a0, a1, a2, a3, 12)
    H_OCT   (a1, a2, a3, a0, 13)
    H_OCT   (a2, a3, a0, a1, 14)
    H_OCT_NP(a3, a0, a1, a2, 15)

    // ---- store: round-trip through LDS for full-line coalescing ----------
    // sm reused as 8 rows x 512 floats (16 KB). Swizzled b128 writes land
    // at the bank floor (phys mod 8 covers each quad exactly 8x per wave).
    __syncthreads();                                 // H-phase reads done
    {
        const float k2 = inv_s2;
        float* wr = sm + r * 512;
        #pragma unroll
        for (int k = 0; k < 4; ++k) {
            const int u  = 4 * L + k;
            const int ph = (u ^ ((u >> 3) & 7)) << 2;
            *(float4*)(wr + ph) = make_float4(acc[4 * k]     * k2,
                                              acc[4 * k + 1] * k2,
                                              acc[4 * k + 2] * k2,
                                              acc[4 * k + 3] * k2);
        }
    }
    __syncthreads();
    {
        float* __restrict__ ob = out + (size_t)plane * PLANE
                                     + (size_t)r0 * WW;
        #pragma unroll
        for (int p = 0; p < 4; ++p) {
            const int U   = p * 256 + tid;           // 0..1023 units
            const int row = U >> 7;                  // 0..7
            const int cu  = U & 127;                 // col unit in row
            const int ph  = (cu ^ ((cu >> 3) & 7)) << 2;
            const float4 v = *(const float4*)(sm + row * 512 + ph);
            *(float4*)(ob + (size_t)row * WW + cu * 4) = v;
        }
    }
}

extern "C" void kernel_launch(void* const* d_in, const int* in_sizes, int n_in,
                              void* d_out, int out_size, void* d_ws, size_t ws_size,
                              hipStream_t stream) {
    const float* x     = (const float*)d_in[0];
    const float* sigma = (const float*)d_in[1];
    float* out = (float*)d_out;
    blur_fused<<<dim3(HH / 8, NIMG), dim3(256), 0, stream>>>(x, sigma, out);
}

// Round 5
// 125.871 us; speedup vs baseline: 1.7528x; 1.7528x over previous
//
#include <hip/hip_runtime.h>

// Depthwise Gaussian blur K=121, replicate pad, separable, fp32. FUSED.
// R12 = R10's 16-col-span H phase (18 group loads/lane vs R9's 38,
// conflicts -62%) + R9's PROVEN store geometry (paired 32B-stride float4,
// WRITE=1.1x output in R7/R9), reached via an in-register xor-16 lane
// exchange: lane A(bit4=0, cols 16L..+15) and B(cols 16L+256..+271) swap
// accumulator halves (8x __shfl_xor(,16)) so A stores 16L..+7 & +256..,
// B stores 16L+8..+15 & +264.. -- R11's LDS-roundtrip store is DELETED
// (it exploded traffic to FETCH 146MB / WRITE 339MB, dur 164us; R10's
// direct 64B-stride stores were 91MB. Only the paired-32B pattern
// write-combines cleanly in L2).
// Kept: 16B-unit XOR swizzle zero-pad LDS, deferred normalization,
// interior clamp-free V path, XCD swizzle.

#define HH    512
#define WW    512
#define PLANE (512 * 512)
#define NIMG  24
#define ROWF  640                    // 160 16B-units/row, swizzle-bijective

__device__ __forceinline__ void make_weights(const float* __restrict__ sigma,
                                             float* __restrict__ wlds, int tid) {
    if (tid < 128) {
        const float s = sigma[0] * 8.0f + 16.0f;
        const float inv2v = 1.0f / (2.0f * s * s);
        float g = 0.0f;
        if (tid < 121) {
            const float c = (float)tid - 60.0f;
            g = __expf(-c * c * inv2v);
        }
        wlds[tid] = g;               // UNNORMALIZED; taps 121..127 exactly 0
    }
}

// dword offset within an LDS row for padded column `col` (swizzled)
__device__ __forceinline__ int swz_off(int col) {
    const int u = col >> 2;
    return ((u ^ ((u >> 3) & 7)) << 2) + (col & 3);
}

// Vertical octet, clamped rows (boundary tiles)
#define V_OCT(CUR, NXT, KO)                                               \
    { *(float4*)&wq[0] = *(const float4*)&wlds[(KO) * 8];                 \
      *(float4*)&wq[4] = *(const float4*)&wlds[(KO) * 8 + 4];             \
      _Pragma("unroll")                                                   \
      for (int ki = 0; ki < 8; ++ki) {                                    \
          int rr = r0 - 52 + (KO) * 8 + ki;                               \
          rr = rr < 0 ? 0 : (rr > HH - 1 ? HH - 1 : rr);                  \
          NXT[ki] = *(const float2*)&src[(size_t)rr * WW];                \
          const float wk = wq[ki];                                        \
          _Pragma("unroll")                                               \
          for (int j = 0; j < 8; ++j) {                                   \
              const int idx = ki + j;                                     \
              const float2 v = (idx < 8) ? CUR[idx] : NXT[idx - 8];       \
              vac[j].x += wk * v.x; vac[j].y += wk * v.y;                 \
          }                                                               \
      }                                                                   \
    }

// Vertical octet, no clamp (interior tiles): running row pointer pv
#define V_OCT_NC(CUR, NXT, KO)                                            \
    { *(float4*)&wq[0] = *(const float4*)&wlds[(KO) * 8];                 \
      *(float4*)&wq[4] = *(const float4*)&wlds[(KO) * 8 + 4];             \
      _Pragma("unroll")                                                   \
      for (int ki = 0; ki < 8; ++ki) {                                    \
          NXT[ki] = *(const float2*)pv; pv += WW;                         \
          const float wk = wq[ki];                                        \
          _Pragma("unroll")                                               \
          for (int j = 0; j < 8; ++j) {                                   \
              const int idx = ki + j;                                     \
              const float2 v = (idx < 8) ? CUR[idx] : NXT[idx - 8];       \
              vac[j].x += wk * v.x; vac[j].y += wk * v.y;                 \
          }                                                               \
      }                                                                   \
    }

// Load group G (8 floats): phys(2G+1) = phys(2G)^1 -> one addr calc / 2 b128
#define LOADG(D, G)                                                       \
    { const int u_  = 2 * (G);                                            \
      const int o1_ = (u_ ^ ((u_ >> 3) & 7)) << 2;                        \
      *(float4*)&D[0] = *(const float4*)(bs + o1_);                       \
      *(float4*)&D[4] = *(const float4*)(bs + (o1_ ^ 4)); }

// One octet over a contiguous 16-col span; window groups A0..A2, prefetch A3
#define H_OCT(A0, A1, A2, A3, KO)                                         \
    { LOADG(A3, 2 * L + (KO) + 3)                                         \
      *(float4*)&wq[0] = *(const float4*)&wlds[(KO) * 8];                 \
      *(float4*)&wq[4] = *(const float4*)&wlds[(KO) * 8 + 4];             \
      _Pragma("unroll")                                                   \
      for (int ki = 0; ki < 8; ++ki) {                                    \
          const float wk = wq[ki];                                        \
          _Pragma("unroll")                                               \
          for (int j = 0; j < 16; ++j) {                                  \
              const int idx = ki + j;                                     \
              const float v = (idx < 8) ? A0[idx]                         \
                            : (idx < 16) ? A1[idx - 8] : A2[idx - 16];    \
              acc[j] += wk * v;                                           \
          }                                                               \
      }                                                                   \
    }

// Final octet: no prefetch (group 2L+18 would run past the row)
#define H_OCT_NP(A0, A1, A2, A3, KO)                                      \
    { *(float4*)&wq[0] = *(const float4*)&wlds[(KO) * 8];                 \
      *(float4*)&wq[4] = *(const float4*)&wlds[(KO) * 8 + 4];             \
      _Pragma("unroll")                                                   \
      for (int ki = 0; ki < 8; ++ki) {                                    \
          const float wk = wq[ki];                                        \
          _Pragma("unroll")                                               \
          for (int j = 0; j < 16; ++j) {                                  \
              const int idx = ki + j;                                     \
              const float v = (idx < 8) ? A0[idx]                         \
                            : (idx < 16) ? A1[idx - 8] : A2[idx - 16];    \
              acc[j] += wk * v;                                           \
          }                                                               \
      }                                                                   \
    }

__global__ __launch_bounds__(256, 6) void blur_fused(
        const float* __restrict__ x, const float* __restrict__ sigma,
        float* __restrict__ out) {
    __shared__ float sm[8 * ROWF];                   // 20480 B
    __shared__ float wlds[128];
    const int tid = threadIdx.x;

    // XCD swizzle: linear id -> contiguous 192-tile span per XCD (%8 rr).
    const int lid   = blockIdx.x + gridDim.x * blockIdx.y;   // 0..1535
    const int tile  = (lid & 7) * 192 + (lid >> 3);
    const int r0    = (tile & 63) * 8;               // output rows r0..r0+7
    const int plane = tile >> 6;

    const int c0 = tid * 2;                          // this thread's 2 cols
    const float* __restrict__ src = x + (size_t)plane * PLANE + c0;

    // ---- vertical: 8 rows x 2 cols per thread, global-streamed window ----
    float2 wa[8], wb[8], vac[8];
    float  wq[8];
    const bool interior = (r0 >= 64) && (r0 <= 432);   // rows r0-60..r0+75 in-range
    if (interior) {
        const float* pp = src + (size_t)(r0 - 60) * WW;
        #pragma unroll
        for (int m = 0; m < 8; ++m) { wa[m] = *(const float2*)pp; pp += WW; }
    } else {
        #pragma unroll
        for (int m = 0; m < 8; ++m) {                // rows r0-60..r0-53
            int rr = r0 - 60 + m;
            rr = rr < 0 ? 0 : rr;
            wa[m] = *(const float2*)&src[(size_t)rr * WW];
        }
    }
    make_weights(sigma, wlds, tid);                  // overlaps loads in flight
    #pragma unroll
    for (int j = 0; j < 8; ++j) vac[j] = make_float2(0.f, 0.f);
    __syncthreads();                                 // wlds ready

    // normalizer: S = sum of taps, once per wave (butterfly), scale at end
    const int lane = tid & 63;
    float s_sum = wlds[lane] + wlds[lane + 64];
    #pragma unroll
    for (int o = 32; o >= 1; o >>= 1) s_sum += __shfl_xor(s_sum, o);
    const float inv_s2 = 1.0f / (s_sum * s_sum);

    if (interior) {
        const float* pv = src + (size_t)(r0 - 52) * WW;
        #pragma unroll 1
        for (int ko = 0; ko < 16; ko += 2) {
            V_OCT_NC(wa, wb, ko)
            V_OCT_NC(wb, wa, ko + 1)
        }
    } else {
        #pragma unroll 1
        for (int ko = 0; ko < 16; ko += 2) {
            V_OCT(wa, wb, ko)
            V_OCT(wb, wa, ko + 1)
        }
    }

    // write intermediate at halo offset +60 (swizzled; float2 stays in-unit)
    {
        const int off = swz_off(c0 + 60);            // col even -> within-unit
        #pragma unroll
        for (int j = 0; j < 8; ++j)
            *(float2*)&sm[j * ROWF + off] = vac[j];
    }
    __syncthreads();

    // ---- halo: cols 0..59 <- col 60; 572..639 <- col 571 -----------------
    // (cols 632..639 are only touched by zero taps; replicate value is fine)
    if (tid < 32) {
        const int p = (tid < 15) ? tid * 4 : 572 + (tid - 15) * 4;
        const int u   = p >> 2;
        const int off = (u ^ ((u >> 3) & 7)) << 2;   // 16B-aligned
        const int soff = (tid < 15) ? swz_off(60) : swz_off(571);
        #pragma unroll
        for (int r8 = 0; r8 < 8; ++r8) {
            const float v = sm[r8 * ROWF + soff];
            *(float4*)&sm[r8 * ROWF + off] = make_float4(v, v, v, v);
        }
    }
    __syncthreads();

    // ---- horizontal: ONE contiguous 16-col span per lane -----------------
    const int r = tid >> 5;                          // 0..7
    const int L = tid & 31;                          // span cols 16L..16L+15
    const float* __restrict__ bs = sm + r * ROWF;

    float a0[8], a1[8], a2[8], a3[8];
    float acc[16];
    #pragma unroll
    for (int j = 0; j < 16; ++j) acc[j] = 0.0f;

    LOADG(a0, 2 * L)
    LOADG(a1, 2 * L + 1)
    LOADG(a2, 2 * L + 2)

    #pragma unroll 1
    for (int ko = 0; ko < 12; ko += 4) {
        H_OCT(a0, a1, a2, a3, ko)
        H_OCT(a1, a2, a3, a0, ko + 1)
        H_OCT(a2, a3, a0, a1, ko + 2)
        H_OCT(a3, a0, a1, a2, ko + 3)
    }
    H_OCT   (a0, a1, a2, a3, 12)
    H_OCT   (a1, a2, a3, a0, 13)
    H_OCT   (a2, a3, a0, a1, 14)
    H_OCT_NP(a3, a0, a1, a2, 15)

    // ---- store: xor-16 lane exchange -> R9's paired 32B-stride pattern ---
    // Lane A (sel=0): keeps cols 16L..+7, receives partner's 16L+256..+263.
    // Lane B (sel=1): receives cols 16(L&15)+8..+15, keeps +264..+271.
    {
        const float k2  = inv_s2;
        const int   sel = (L >> 4) & 1;
        float blk1[8], blk2[8];
        #pragma unroll
        for (int j = 0; j < 8; ++j) {
            const float send = sel ? acc[j] : acc[j + 8];
            const float recv = __shfl_xor(send, 16, 64);
            blk1[j] = (sel ? recv : acc[j]) * k2;
            blk2[j] = (sel ? acc[j + 8] : recv) * k2;
        }
        float* __restrict__ dst = out + (size_t)plane * PLANE
                                      + (size_t)(r0 + r) * WW
                                      + 16 * (L & 15) + sel * 8;
        *(float4*)(dst)       = make_float4(blk1[0], blk1[1], blk1[2], blk1[3]);
        *(float4*)(dst + 4)   = make_float4(blk1[4], blk1[5], blk1[6], blk1[7]);
        *(float4*)(dst + 256) = make_float4(blk2[0], blk2[1], blk2[2], blk2[3]);
        *(float4*)(dst + 260) = make_float4(blk2[4], blk2[5], blk2[6], blk2[7]);
    }
}

extern "C" void kernel_launch(void* const* d_in, const int* in_sizes, int n_in,
                              void* d_out, int out_size, void* d_ws, size_t ws_size,
                              hipStream_t stream) {
    const float* x     = (const float*)d_in[0];
    const float* sigma = (const float*)d_in[1];
    float* out = (float*)d_out;
    blur_fused<<<dim3(HH / 8, NIMG), dim3(256), 0, stream>>>(x, sigma, out);
}

// Round 6
// 116.242 us; speedup vs baseline: 1.8980x; 1.0828x over previous
//
#include <hip/hip_runtime.h>

// Depthwise Gaussian blur K=121, replicate pad, separable, fp32. FUSED.
// R13 = R9 (the 55.5us, clean-traffic config: two 8-col H spans, paired
// 32B-stride stores, clamped V, ROWF 672) with ONE surgical LDS-side cut:
// weights move from LDS broadcasts (2x ds_read_b128 per octet x 32 octets
// = 64 LDS ops/lane) to SCALAR loads from d_ws. A 1-block pre-kernel
// writes the 128 NORMALIZED 1-D taps; the main kernel reads them via
// uniform-pointer/uniform-index loads -> s_load_dwordx4 (K$, lgkm pipe,
// zero LDS pressure). Also deleted: wlds, the early barrier, the wave
// butterfly, and the 1/S^2 epilogue multiply (taps pre-normalized; the
// separable product reproduces the reference's 2-D normalization exactly).
// R10/R11/R12 lesson: any restructure of the H/store path inflated HBM
// WRITE 2.7-13x despite provably identical store address sets -> revert
// all global-side code to R9 verbatim, optimize only CU-side.

#define HH    512
#define WW    512
#define PLANE (512 * 512)
#define NIMG  24
#define ROWF  672                    // 168 16B-units/row, swizzle-bijective

// ---- pre-kernel: 128 normalized 1-D taps -> d_ws --------------------------
__global__ void wk_prep(const float* __restrict__ sigma,
                        float* __restrict__ wg) {
    const int tid = threadIdx.x;                     // 128 threads, 1 block
    const float s = sigma[0] * 8.0f + 16.0f;
    const float inv2v = 1.0f / (2.0f * s * s);
    float sum = 0.0f;
    #pragma unroll
    for (int k = 0; k <= 120; ++k) {
        const float c = (float)k - 60.0f;
        sum += __expf(-c * c * inv2v);
    }
    float g = 0.0f;
    if (tid < 121) {
        const float c = (float)tid - 60.0f;
        g = __expf(-c * c * inv2v);
    }
    wg[tid] = g / sum;               // taps 121..127 exactly 0
}

// dword offset within an LDS row for padded column `col` (swizzled)
__device__ __forceinline__ int swz_off(int col) {
    const int u = col >> 2;
    return ((u ^ ((u >> 3) & 7)) << 2) + (col & 3);
}

// Vertical octet: prefetch next 8 window rows (float2, clamped), 8 taps x
// 8 output rows. Weights come from wg (uniform -> scalar loads).
#define V_OCT(CUR, NXT, KO)                                               \
    { *(float4*)&wq[0] = *(const float4*)&wg[(KO) * 8];                   \
      *(float4*)&wq[4] = *(const float4*)&wg[(KO) * 8 + 4];               \
      _Pragma("unroll")                                                   \
      for (int ki = 0; ki < 8; ++ki) {                                    \
          int rr = r0 - 52 + (KO) * 8 + ki;                               \
          rr = rr < 0 ? 0 : (rr > HH - 1 ? HH - 1 : rr);                  \
          NXT[ki] = *(const float2*)&src[(size_t)rr * WW];                \
          const float wk = wq[ki];                                        \
          _Pragma("unroll")                                               \
          for (int j = 0; j < 8; ++j) {                                   \
              const int idx = ki + j;                                     \
              const float2 v = (idx < 8) ? CUR[idx] : NXT[idx - 8];       \
              vac[j].x += wk * v.x; vac[j].y += wk * v.y;                 \
          }                                                               \
      }                                                                   \
    }

// Load group G (span A) and G+32 (span B): one swizzled address serves all
// four b128s -- phys(2G+1)=phys(2G)^1 (same octave), phys(u+64)=phys(u)+64,
// so span B is a constant +64 units = +256 floats.
#define LOADG2(DA, DB, G)                                                 \
    { const int u_  = 2 * (G);                                            \
      const int o1_ = (u_ ^ ((u_ >> 3) & 7)) << 2;                        \
      const int o2_ = o1_ ^ 4;                                            \
      *(float4*)&DA[0] = *(const float4*)(bs + o1_);                      \
      *(float4*)&DA[4] = *(const float4*)(bs + o2_);                      \
      *(float4*)&DB[0] = *(const float4*)(bs + o1_ + 256);                \
      *(float4*)&DB[4] = *(const float4*)(bs + o2_ + 256); }

// One octet, TWO 8-col spans (A: groups L+.., B: groups L+32+..)
#define H_OCT2(A0, A1, A2, A3, B0, B1, B2, B3, KO)                        \
    { LOADG2(A3, B3, L + (KO) + 3)                                        \
      *(float4*)&wq[0] = *(const float4*)&wg[(KO) * 8];                   \
      *(float4*)&wq[4] = *(const float4*)&wg[(KO) * 8 + 4];               \
      _Pragma("unroll")                                                   \
      for (int ki = 0; ki < 8; ++ki) {                                    \
          const float wk = wq[ki];                                        \
          _Pragma("unroll")                                               \
          for (int j = 0; j < 8; ++j) {                                   \
              const int idx = ki + j;                                     \
              const float vA = (idx < 8) ? A0[idx]                        \
                             : (idx < 16) ? A1[idx - 8] : A2[idx - 16];   \
              const float vB = (idx < 8) ? B0[idx]                        \
                             : (idx < 16) ? B1[idx - 8] : B2[idx - 16];   \
              accA[j] += wk * vA;                                         \
              accB[j] += wk * vB;                                         \
          }                                                               \
      }                                                                   \
    }

__global__ __launch_bounds__(256, 6) void blur_fused(
        const float* __restrict__ x, const float* __restrict__ wg,
        float* __restrict__ out) {
    __shared__ float sm[8 * ROWF];                   // 21504 B
    const int tid = threadIdx.x;

    // XCD swizzle: linear id -> contiguous 192-tile span per XCD (%8 rr).
    const int lid   = blockIdx.x + gridDim.x * blockIdx.y;   // 0..1535
    const int tile  = (lid & 7) * 192 + (lid >> 3);
    const int r0    = (tile & 63) * 8;               // output rows r0..r0+7
    const int plane = tile >> 6;

    const int c0 = tid * 2;                          // this thread's 2 cols
    const float* __restrict__ src = x + (size_t)plane * PLANE + c0;

    // ---- vertical: 8 rows x 2 cols per thread, global-streamed window ----
    float2 wa[8], wb[8], vac[8];
    float  wq[8];
    #pragma unroll
    for (int m = 0; m < 8; ++m) {                    // rows r0-60..r0-53
        int rr = r0 - 60 + m;
        rr = rr < 0 ? 0 : rr;
        wa[m] = *(const float2*)&src[(size_t)rr * WW];
    }
    #pragma unroll
    for (int j = 0; j < 8; ++j) vac[j] = make_float2(0.f, 0.f);

    #pragma unroll 1
    for (int ko = 0; ko < 16; ko += 2) {
        V_OCT(wa, wb, ko)
        V_OCT(wb, wa, ko + 1)
    }

    // write intermediate at halo offset +60 (swizzled; float2 stays in-unit)
    {
        const int off = swz_off(c0 + 60);            // col even -> within-unit
        #pragma unroll
        for (int j = 0; j < 8; ++j)
            *(float2*)&sm[j * ROWF + off] = vac[j];
    }
    __syncthreads();

    // ---- halo: idx 0..59 <- 60; 572..647 <- 571; zero 648..655 -----------
    if (tid < 36) {
        const int p = (tid < 15) ? tid * 4
                    : (tid < 34) ? 572 + (tid - 15) * 4
                                 : 648 + (tid - 34) * 4;
        const int u   = p >> 2;
        const int off = (u ^ ((u >> 3) & 7)) << 2;   // 16B-aligned
        const int soff = (tid < 15) ? swz_off(60) : swz_off(571);
        #pragma unroll
        for (int r8 = 0; r8 < 8; ++r8) {
            const float v = (tid < 34) ? sm[r8 * ROWF + soff] : 0.0f;
            *(float4*)&sm[r8 * ROWF + off] = make_float4(v, v, v, v);
        }
    }
    __syncthreads();

    // ---- horizontal: two 8-col spans per lane, rotating 4-octet windows --
    const int r = tid >> 5;                          // 0..7
    const int L = tid & 31;                          // span A cols 8L.., B +256
    const float* __restrict__ bs = sm + r * ROWF;

    float a0[8], a1[8], a2[8], a3[8];
    float b0[8], b1[8], b2[8], b3[8];
    float accA[8], accB[8];
    #pragma unroll
    for (int j = 0; j < 8; ++j) { accA[j] = 0.0f; accB[j] = 0.0f; }

    LOADG2(a0, b0, L)
    LOADG2(a1, b1, L + 1)
    LOADG2(a2, b2, L + 2)

    #pragma unroll 1
    for (int ko = 0; ko < 16; ko += 4) {
        H_OCT2(a0, a1, a2, a3, b0, b1, b2, b3, ko)
        H_OCT2(a1, a2, a3, a0, b1, b2, b3, b0, ko + 1)
        H_OCT2(a2, a3, a0, a1, b2, b3, b0, b1, ko + 2)
        H_OCT2(a3, a0, a1, a2, b3, b0, b1, b2, ko + 3)
    }

    float* __restrict__ dst = out + (size_t)plane * PLANE
                                  + (size_t)(r0 + r) * WW + L * 8;
    *(float4*)(dst)       = make_float4(accA[0], accA[1], accA[2], accA[3]);
    *(float4*)(dst + 4)   = make_float4(accA[4], accA[5], accA[6], accA[7]);
    *(float4*)(dst + 256) = make_float4(accB[0], accB[1], accB[2], accB[3]);
    *(float4*)(dst + 260) = make_float4(accB[4], accB[5], accB[6], accB[7]);
}

extern "C" void kernel_launch(void* const* d_in, const int* in_sizes, int n_in,
                              void* d_out, int out_size, void* d_ws, size_t ws_size,
                              hipStream_t stream) {
    const float* x     = (const float*)d_in[0];
    const float* sigma = (const float*)d_in[1];
    float* out = (float*)d_out;
    float* wg  = (float*)d_ws;                       // 512 B of workspace
    wk_prep<<<dim3(1), dim3(128), 0, stream>>>(sigma, wg);
    blur_fused<<<dim3(HH / 8, NIMG), dim3(256), 0, stream>>>(x, wg, out);
}